// Round 1
// baseline (387.748 us; speedup 1.0000x reference)
//
#include <hip/hip_runtime.h>

// Shapes (fixed per setup_inputs): n=1, C=256, t=8, h=64, w=64, heads=8, S=134
#define SS   134
#define HWP  4096     // h*w
#define THW  32768    // t*h*w

typedef float f32x4 __attribute__((ext_vector_type(4)));
typedef short bf16x8 __attribute__((ext_vector_type(8)));
typedef short bf16x4 __attribute__((ext_vector_type(4)));

__device__ __forceinline__ unsigned short f2bf(float f) {
  unsigned int u = __float_as_uint(f);
  u += 0x7fff + ((u >> 16) & 1);  // RNE (inputs are finite normals)
  return (unsigned short)(u >> 16);
}

// ---------------------------------------------------------------------------
// 1x1 conv as bf16-MFMA GEMM: PV[o][x] = sum_c W[o][c] * V[c][x] + bias[o]
// (unchanged)
// ---------------------------------------------------------------------------
__global__ __launch_bounds__(256) void conv1x1_v2(
    const float* __restrict__ V, const float* __restrict__ W,
    const float* __restrict__ bias, float* __restrict__ PV) {
  __shared__ unsigned short sW[256 * 40];  // [o][c-k0], bf16, row stride 40
  __shared__ unsigned short sV[32 * 40];   // [x][c-k0], bf16 (transposed)
  const int tid = threadIdx.x;
  const int x0 = blockIdx.x * 32;
  const int lane = tid & 63;
  const int wv = tid >> 6;   // wave 0..3
  const int m = lane & 15;   // MFMA free-dim index
  const int q = lane >> 4;   // MFMA quad 0..3

  f32x4 acc[4][2];
#pragma unroll
  for (int i = 0; i < 4; ++i)
#pragma unroll
    for (int j = 0; j < 2; ++j)
      acc[i][j] = (f32x4){0.f, 0.f, 0.f, 0.f};

  for (int k0 = 0; k0 < 256; k0 += 32) {
#pragma unroll 2
    for (int r = 0; r < 8; ++r) {
      const int f = r * 256 + tid;
      const int o = f >> 3;
      const int c4 = (f & 7) * 4;
      const float4 w4 = *(const float4*)&W[o * 256 + k0 + c4];
      bf16x4 b;
      b.x = (short)f2bf(w4.x);
      b.y = (short)f2bf(w4.y);
      b.z = (short)f2bf(w4.z);
      b.w = (short)f2bf(w4.w);
      *(bf16x4*)&sW[o * 40 + c4] = b;
    }
    {
      const int c = tid >> 3;          // 0..31
      const int x4 = (tid & 7) * 4;    // 0..28
      const float4 v4 = *(const float4*)&V[(size_t)(k0 + c) * THW + x0 + x4];
      sV[(x4 + 0) * 40 + c] = f2bf(v4.x);
      sV[(x4 + 1) * 40 + c] = f2bf(v4.y);
      sV[(x4 + 2) * 40 + c] = f2bf(v4.z);
      sV[(x4 + 3) * 40 + c] = f2bf(v4.w);
    }
    __syncthreads();
    bf16x8 fa[4], fb[2];
#pragma unroll
    for (int i = 0; i < 4; ++i)
      fa[i] = *(const bf16x8*)&sW[(wv * 64 + i * 16 + m) * 40 + q * 8];
#pragma unroll
    for (int j = 0; j < 2; ++j)
      fb[j] = *(const bf16x8*)&sV[(j * 16 + m) * 40 + q * 8];
#pragma unroll
    for (int i = 0; i < 4; ++i)
#pragma unroll
      for (int j = 0; j < 2; ++j)
        acc[i][j] = __builtin_amdgcn_mfma_f32_16x16x32_bf16(fa[i], fb[j], acc[i][j], 0, 0, 0);
    __syncthreads();
  }

#pragma unroll
  for (int i = 0; i < 4; ++i) {
#pragma unroll
    for (int r = 0; r < 4; ++r) {
      const int o = wv * 64 + i * 16 + q * 4 + r;
      const float b = bias[o];
#pragma unroll
      for (int j = 0; j < 2; ++j)
        PV[(size_t)o * THW + x0 + j * 16 + m] = acc[i][j][r] + b;
    }
  }
}

// ---------------------------------------------------------------------------
// t + h axes. Block = (hd, tq, w-strip of 8). NOW 512 thr (16 waves/CU at
// 2 blocks/CU instead of 8 — attn_th was latency-bound at 18% occupancy):
//   w4 = (tid&1)*4 (2 w-quads), q16 = (tid>>1)&15, qh = (tid>>5)&1 (q-half),
//   cg = tid>>6 (channels cg + 8*ci, ci=0..3). acc[2 qq][4 ci] f32x4 over w.
// Block-index decode swizzled: b = tq + 8*hd + 64*wb, so the 8 wb-siblings
// (which touch complementary 32B chunks of the same A/PV cachelines) share
// b%8 → same XCD → L2 absorbs the 4x line over-fetch.
// pv h-slab [32c][64p][8w] fp32 in LDS (64 KB): h-source reads are pure
// LDS broadcasts. A h-row select per (p,qq): row = p - (q<p), a=0 if q==p.
// ---------------------------------------------------------------------------
__global__ __launch_bounds__(512, 4) void attn_th(
    const float* __restrict__ A, const float* __restrict__ PV,
    float* __restrict__ O) {
  const int b = blockIdx.x;  // tq + 8*hd + 64*wb, grid 512
  const int tq = b & 7;
  const int hd = (b >> 3) & 7;
  const int wb = b >> 6;
  const int tid = threadIdx.x;
  const int w4 = (tid & 1) * 4;
  const int q16 = (tid >> 1) & 15;
  const int qh = (tid >> 5) & 1;  // q-half within wave
  const int cg = tid >> 6;        // 0..7 (wave-uniform)

  __shared__ float slab[32 * 64 * 8];  // [c][p][w8]

  const float* __restrict__ Ab = A + (size_t)hd * SS * THW + (size_t)tq * HWP;
  const size_t pvh = (size_t)hd * 32 * THW;

  // stage pv h-slab: pv[hd*32+c][tq][p][wb*8 + w]
#pragma unroll
  for (int i = 0; i < 8; ++i) {
    const int fid = tid + i * 512;  // 0..4095
    const int ws = (fid & 1) * 4;
    const int p = (fid >> 1) & 63;
    const int c = fid >> 7;  // 0..31
    *(f32x4*)&slab[(c * 64 + p) * 8 + ws] =
        *(const f32x4*)&PV[pvh + (size_t)c * THW + (size_t)tq * HWP + p * 64 + wb * 8 + ws];
  }
  __syncthreads();

  f32x4 acc[2][4];  // [qq][ci]
#pragma unroll
  for (int i = 0; i < 2; ++i)
#pragma unroll
    for (int j = 0; j < 4; ++j)
      acc[i][j] = (f32x4){0.f, 0.f, 0.f, 0.f};

  // ---- t axis (pv from global, L2-warm) ----
  for (int s = 0; s < 8; ++s) {
#pragma unroll
    for (int qq = 0; qq < 2; ++qq) {
      const int q = (qh * 2 + qq) * 16 + q16;
      const f32x4 a = *(const f32x4*)&Ab[(size_t)s * THW + q * 64 + wb * 8 + w4];
#pragma unroll
      for (int ci = 0; ci < 4; ++ci) {
        const int c = cg + ci * 8;
        const f32x4 v =
            *(const f32x4*)&PV[pvh + (size_t)c * THW + (size_t)s * HWP + q * 64 + wb * 8 + w4];
        acc[qq][ci] += a * v;
      }
    }
  }

  // ---- h axis ----
  const float* __restrict__ Ah = Ab + (size_t)8 * THW + wb * 8 + w4;
#pragma unroll 2
  for (int p = 0; p < 64; ++p) {
    f32x4 av[2];
#pragma unroll
    for (int qq = 0; qq < 2; ++qq) {
      const int q = (qh * 2 + qq) * 16 + q16;
      const int row = p - (q < p ? 1 : 0);  // 0..62 (p==q garbage, masked)
      f32x4 a = *(const f32x4*)&Ah[(size_t)row * THW + q * 64];
      if (q == p) a = (f32x4){0.f, 0.f, 0.f, 0.f};
      av[qq] = a;
    }
    f32x4 vv[4];
#pragma unroll
    for (int ci = 0; ci < 4; ++ci)
      vv[ci] = *(const f32x4*)&slab[((cg + ci * 8) * 64 + p) * 8 + w4];
#pragma unroll
    for (int qq = 0; qq < 2; ++qq)
#pragma unroll
      for (int ci = 0; ci < 4; ++ci)
        acc[qq][ci] += av[qq] * vv[ci];
  }

  // ---- store ----
#pragma unroll
  for (int qq = 0; qq < 2; ++qq) {
    const int q = (qh * 2 + qq) * 16 + q16;
#pragma unroll
    for (int ci = 0; ci < 4; ++ci) {
      const int c = cg + ci * 8;
      *(f32x4*)&O[pvh + (size_t)c * THW + (size_t)tq * HWP + q * 64 + wb * 8 + w4] =
          acc[qq][ci];
    }
  }
}

// ---------------------------------------------------------------------------
// w axis, read-modify-write on O. Block = (hd, tq, h-strip of 4). 256 thr:
//   wq = tid&63 (lane = output w), cg = tid>>6 (channels cg + 4*ci, ci=0..7).
// pv w-slab [32c][64pw][4h] fp32 in LDS (32 KB): source reads are uniform
// f32x4 broadcasts. Weight row per (p, lane): r = 71 + p - (wq<=p), a=0 if
// p==wq (wq<=p avoids OOB row 134 at p==wq==63).
// acc[8 ci] f32x4 over h.  (unchanged)
// ---------------------------------------------------------------------------
__global__ __launch_bounds__(256) void attn_w(
    const float* __restrict__ A, const float* __restrict__ PV,
    float* __restrict__ O) {
  const int b = blockIdx.x;  // hb + 16*tq + 128*hd, grid 1024
  const int hb = b & 15;
  const int tq = (b >> 4) & 7;
  const int hd = b >> 7;
  const int tid = threadIdx.x;
  const int wq = tid & 63;
  const int cg = tid >> 6;  // 0..3
  const int h0 = hb * 4;

  __shared__ float slab[32 * 64 * 4];  // [c][pw][h4]

  const float* __restrict__ Ab = A + (size_t)hd * SS * THW + (size_t)tq * HWP;
  const size_t pvh = (size_t)hd * 32 * THW;

  // stage pv w-slab (transpose w<->h minor dims)
#pragma unroll 4
  for (int i = 0; i < 8; ++i) {
    const int fid = tid + i * 256;     // 0..2047
    const int w4s = (fid & 15) * 4;    // 0..60
    const int h = (fid >> 4) & 3;      // 0..3
    const int c = fid >> 6;            // 0..31
    const f32x4 v =
        *(const f32x4*)&PV[pvh + (size_t)c * THW + (size_t)tq * HWP + (h0 + h) * 64 + w4s];
    slab[(c * 64 + w4s + 0) * 4 + h] = v.x;
    slab[(c * 64 + w4s + 1) * 4 + h] = v.y;
    slab[(c * 64 + w4s + 2) * 4 + h] = v.z;
    slab[(c * 64 + w4s + 3) * 4 + h] = v.w;
  }

  // prefetch current O tile (RMW) while staging completes
  f32x4 racc[8];
#pragma unroll
  for (int ci = 0; ci < 8; ++ci) {
    const int c = cg + ci * 4;
    f32x4 r;
#pragma unroll
    for (int hh = 0; hh < 4; ++hh)
      r[hh] = O[pvh + (size_t)c * THW + (size_t)tq * HWP + (h0 + hh) * 64 + wq];
    racc[ci] = r;
  }
  __syncthreads();

#pragma unroll 2
  for (int p = 0; p < 64; ++p) {
    const int row = 71 + p - (wq <= p ? 1 : 0);  // 70..133, in-bounds always
    const float* pa = Ab + (size_t)row * THW + h0 * 64 + wq;
    f32x4 a;
    a.x = pa[0];
    a.y = pa[64];
    a.z = pa[128];
    a.w = pa[192];
    if (p == wq) a = (f32x4){0.f, 0.f, 0.f, 0.f};
#pragma unroll
    for (int ci = 0; ci < 8; ++ci) {
      const f32x4 v = *(const f32x4*)&slab[(cg + ci * 4) * 256 + p * 4];
      racc[ci] += a * v;
    }
  }

  // ---- store (RMW result) ----
#pragma unroll
  for (int ci = 0; ci < 8; ++ci) {
    const int c = cg + ci * 4;
#pragma unroll
    for (int hh = 0; hh < 4; ++hh)
      O[pvh + (size_t)c * THW + (size_t)tq * HWP + (h0 + hh) * 64 + wq] = racc[ci][hh];
  }
}

extern "C" void kernel_launch(void* const* d_in, const int* in_sizes, int n_in,
                              void* d_out, int out_size, void* d_ws, size_t ws_size,
                              hipStream_t stream) {
  const float* A = (const float*)d_in[0];     // [8*134][8][64][64]
  const float* V = (const float*)d_in[1];     // [256][8][64][64]
  const float* W = (const float*)d_in[2];     // [256][256] (o, c)
  const float* bias = (const float*)d_in[3];  // [256]
  float* out = (float*)d_out;                 // [256][8][64][64]
  float* pv = (float*)d_ws;                   // 32 MB scratch: pv[o][t][h][w]

  conv1x1_v2<<<dim3(1024), 256, 0, stream>>>(V, W, bias, pv);
  attn_th<<<dim3(512), 512, 0, stream>>>(A, pv, out);
  attn_w<<<dim3(1024), 256, 0, stream>>>(A, pv, out);
}

// Round 2
// 347.711 us; speedup vs baseline: 1.1151x; 1.1151x over previous
//
#include <hip/hip_runtime.h>

// Shapes (fixed per setup_inputs): n=1, C=256, t=8, h=64, w=64, heads=8, S=134
#define SS   134
#define HWP  4096     // h*w
#define THW  32768    // t*h*w

typedef float f32x4 __attribute__((ext_vector_type(4)));
typedef short bf16x8 __attribute__((ext_vector_type(8)));
typedef short bf16x4 __attribute__((ext_vector_type(4)));

__device__ __forceinline__ unsigned short f2bf(float f) {
  unsigned int u = __float_as_uint(f);
  u += 0x7fff + ((u >> 16) & 1);  // RNE (inputs are finite normals)
  return (unsigned short)(u >> 16);
}

// ---------------------------------------------------------------------------
// 1x1 conv as bf16-MFMA GEMM: PV[o][x] = sum_c W[o][c] * V[c][x] + bias[o]
// (unchanged)
// ---------------------------------------------------------------------------
__global__ __launch_bounds__(256) void conv1x1_v2(
    const float* __restrict__ V, const float* __restrict__ W,
    const float* __restrict__ bias, float* __restrict__ PV) {
  __shared__ unsigned short sW[256 * 40];  // [o][c-k0], bf16, row stride 40
  __shared__ unsigned short sV[32 * 40];   // [x][c-k0], bf16 (transposed)
  const int tid = threadIdx.x;
  const int x0 = blockIdx.x * 32;
  const int lane = tid & 63;
  const int wv = tid >> 6;   // wave 0..3
  const int m = lane & 15;   // MFMA free-dim index
  const int q = lane >> 4;   // MFMA quad 0..3

  f32x4 acc[4][2];
#pragma unroll
  for (int i = 0; i < 4; ++i)
#pragma unroll
    for (int j = 0; j < 2; ++j)
      acc[i][j] = (f32x4){0.f, 0.f, 0.f, 0.f};

  for (int k0 = 0; k0 < 256; k0 += 32) {
#pragma unroll 2
    for (int r = 0; r < 8; ++r) {
      const int f = r * 256 + tid;
      const int o = f >> 3;
      const int c4 = (f & 7) * 4;
      const float4 w4 = *(const float4*)&W[o * 256 + k0 + c4];
      bf16x4 b;
      b.x = (short)f2bf(w4.x);
      b.y = (short)f2bf(w4.y);
      b.z = (short)f2bf(w4.z);
      b.w = (short)f2bf(w4.w);
      *(bf16x4*)&sW[o * 40 + c4] = b;
    }
    {
      const int c = tid >> 3;          // 0..31
      const int x4 = (tid & 7) * 4;    // 0..28
      const float4 v4 = *(const float4*)&V[(size_t)(k0 + c) * THW + x0 + x4];
      sV[(x4 + 0) * 40 + c] = f2bf(v4.x);
      sV[(x4 + 1) * 40 + c] = f2bf(v4.y);
      sV[(x4 + 2) * 40 + c] = f2bf(v4.z);
      sV[(x4 + 3) * 40 + c] = f2bf(v4.w);
    }
    __syncthreads();
    bf16x8 fa[4], fb[2];
#pragma unroll
    for (int i = 0; i < 4; ++i)
      fa[i] = *(const bf16x8*)&sW[(wv * 64 + i * 16 + m) * 40 + q * 8];
#pragma unroll
    for (int j = 0; j < 2; ++j)
      fb[j] = *(const bf16x8*)&sV[(j * 16 + m) * 40 + q * 8];
#pragma unroll
    for (int i = 0; i < 4; ++i)
#pragma unroll
      for (int j = 0; j < 2; ++j)
        acc[i][j] = __builtin_amdgcn_mfma_f32_16x16x32_bf16(fa[i], fb[j], acc[i][j], 0, 0, 0);
    __syncthreads();
  }

#pragma unroll
  for (int i = 0; i < 4; ++i) {
#pragma unroll
    for (int r = 0; r < 4; ++r) {
      const int o = wv * 64 + i * 16 + q * 4 + r;
      const float b = bias[o];
#pragma unroll
      for (int j = 0; j < 2; ++j)
        PV[(size_t)o * THW + x0 + j * 16 + m] = acc[i][j][r] + b;
    }
  }
}

// ---------------------------------------------------------------------------
// t + h axes, v3: FULL-LINE COALESCING.
// Old layout put a wb*8 w-strip in each lane group -> every global load hit
// 32 cachelines at 25% utilization (TA-bound, ~110K line-txns/CU, flat at
// 146us regardless of occupancy). New layout: lane = (w4 = lane&15 covering
// all w via f32x4, cl = lane>>4 covering 4 consecutive c) -> every global
// load is contiguous 256B..1KB runs; every ds_read_b128 is a contiguous 1KB
// wave read (conflict-free).
//   Block = (hd, tq, qb of 16 q), grid 256, 512 threads (8 waves, 1 blk/CU).
//   Wave: ch = wv&1 (c half), qg = wv>>1 -> q = qb*16 + qg*4 + qi (4 q/thread)
//   Thread c-set: c = ch*16 + g*4 + cl (4 c/thread).
//   acc[4 qi][4 g] f32x4 over w.
// h-axis PV slab double-buffered in LDS, 8-p chunks ([8][32][64] f32 = 64KB
// x2), global->reg prefetch issued before compute (T14 split) so staging
// hides under FMA. A_h row per (p,q): row = p - (q<p), thread-uniform ->
// coalesced; a=0 if q==p.
// ---------------------------------------------------------------------------
__global__ __launch_bounds__(512) void attn_th(
    const float* __restrict__ A, const float* __restrict__ PV,
    float* __restrict__ O) {
  const int b = blockIdx.x;  // hd + 8*(qb + 4*tq), grid 256
  const int hd = b & 7;      // all blocks of one head share b%8 -> same XCD
  const int qb = (b >> 3) & 3;
  const int tq = b >> 5;  // 0..7
  const int tid = threadIdx.x;
  const int lane = tid & 63;
  const int wv = tid >> 6;         // 0..7
  const int w4 = (lane & 15) * 4;  // w float-offset (f32x4)
  const int cl = lane >> 4;        // 0..3
  const int ch = wv & 1;           // c half
  const int qg = wv >> 1;          // 0..3
  const int q0 = qb * 16 + qg * 4;

  __shared__ float slab[2][8 * 32 * 64];  // [buf][pp][c][w]

  const float* __restrict__ Ab = A + (size_t)hd * SS * THW + (size_t)tq * HWP;
  const size_t pvh = (size_t)hd * 32 * THW;
  const float* __restrict__ PVh = PV + pvh;

  f32x4 acc[4][4];  // [qi][g]
#pragma unroll
  for (int i = 0; i < 4; ++i)
#pragma unroll
    for (int j = 0; j < 4; ++j)
      acc[i][j] = (f32x4){0.f, 0.f, 0.f, 0.f};

  // staging map: round r -> pp=r, c_s = tid>>4, w4s = (tid&15)*4
  const int c_s = tid >> 4;
  const int w4s = (tid & 15) * 4;
  const float* __restrict__ pvstage =
      PVh + (size_t)c_s * THW + (size_t)tq * HWP + w4s;
  const int sbase = c_s * 64 + w4s;  // LDS float offset within a pp-plane set

  // issue chunk-0 prefetch (p = 0..7) early; overlaps t-axis compute
  f32x4 stg[8];
#pragma unroll
  for (int r = 0; r < 8; ++r) stg[r] = *(const f32x4*)&pvstage[r * 64];

  // ---- t axis (pure streaming, fully coalesced, no reuse) ----
  for (int s = 0; s < 8; ++s) {
#pragma unroll
    for (int qi = 0; qi < 4; ++qi) {
      const int q = q0 + qi;
      const f32x4 a = *(const f32x4*)&Ab[(size_t)s * THW + q * 64 + w4];
#pragma unroll
      for (int g = 0; g < 4; ++g) {
        const int c = ch * 16 + g * 4 + cl;
        const f32x4 v =
            *(const f32x4*)&PVh[(size_t)c * THW + (size_t)s * HWP + q * 64 + w4];
        acc[qi][g] += a * v;
      }
    }
  }

  // write chunk 0 into buf 0
#pragma unroll
  for (int r = 0; r < 8; ++r)
    *(f32x4*)&slab[0][r * 2048 + sbase] = stg[r];
  __syncthreads();

  // ---- h axis: 8 chunks of 8 p, double-buffered ----
  for (int ck = 0; ck < 8; ++ck) {
    const int cur = ck & 1;
    if (ck < 7) {
      // issue next chunk's global loads now; they complete under the FMAs
#pragma unroll
      for (int r = 0; r < 8; ++r)
        stg[r] = *(const f32x4*)&pvstage[((ck + 1) * 8 + r) * 64];
    }
#pragma unroll
    for (int pp = 0; pp < 8; ++pp) {
      const int p = ck * 8 + pp;
      f32x4 a[4];
#pragma unroll
      for (int qi = 0; qi < 4; ++qi) {
        const int q = q0 + qi;
        const int row = p - (q < p ? 1 : 0);  // 0..63 (p==q load masked)
        f32x4 av = *(const f32x4*)&Ab[(size_t)(8 + row) * THW + q * 64 + w4];
        if (q == p) av = (f32x4){0.f, 0.f, 0.f, 0.f};
        a[qi] = av;
      }
      f32x4 v[4];
#pragma unroll
      for (int g = 0; g < 4; ++g)
        v[g] = *(const f32x4*)&slab[cur][pp * 2048 + (ch * 16 + g * 4 + cl) * 64 + w4];
#pragma unroll
      for (int qi = 0; qi < 4; ++qi)
#pragma unroll
        for (int g = 0; g < 4; ++g)
          acc[qi][g] += a[qi] * v[g];
    }
    __syncthreads();  // all waves done reading buf (ck-1)&1 two chunks ago & cur
    if (ck < 7) {
#pragma unroll
      for (int r = 0; r < 8; ++r)
        *(f32x4*)&slab[cur ^ 1][r * 2048 + sbase] = stg[r];
      __syncthreads();
    }
  }

  // ---- store ----
#pragma unroll
  for (int qi = 0; qi < 4; ++qi) {
    const int q = q0 + qi;
#pragma unroll
    for (int g = 0; g < 4; ++g) {
      const int c = ch * 16 + g * 4 + cl;
      *(f32x4*)&O[pvh + (size_t)c * THW + (size_t)tq * HWP + q * 64 + w4] =
          acc[qi][g];
    }
  }
}

// ---------------------------------------------------------------------------
// w axis, read-modify-write on O. (unchanged this round)
// ---------------------------------------------------------------------------
__global__ __launch_bounds__(256) void attn_w(
    const float* __restrict__ A, const float* __restrict__ PV,
    float* __restrict__ O) {
  const int b = blockIdx.x;  // hb + 16*tq + 128*hd, grid 1024
  const int hb = b & 15;
  const int tq = (b >> 4) & 7;
  const int hd = b >> 7;
  const int tid = threadIdx.x;
  const int wq = tid & 63;
  const int cg = tid >> 6;  // 0..3
  const int h0 = hb * 4;

  __shared__ float slab[32 * 64 * 4];  // [c][pw][h4]

  const float* __restrict__ Ab = A + (size_t)hd * SS * THW + (size_t)tq * HWP;
  const size_t pvh = (size_t)hd * 32 * THW;

  // stage pv w-slab (transpose w<->h minor dims)
#pragma unroll 4
  for (int i = 0; i < 8; ++i) {
    const int fid = tid + i * 256;     // 0..2047
    const int w4s = (fid & 15) * 4;    // 0..60
    const int h = (fid >> 4) & 3;      // 0..3
    const int c = fid >> 6;            // 0..31
    const f32x4 v =
        *(const f32x4*)&PV[pvh + (size_t)c * THW + (size_t)tq * HWP + (h0 + h) * 64 + w4s];
    slab[(c * 64 + w4s + 0) * 4 + h] = v.x;
    slab[(c * 64 + w4s + 1) * 4 + h] = v.y;
    slab[(c * 64 + w4s + 2) * 4 + h] = v.z;
    slab[(c * 64 + w4s + 3) * 4 + h] = v.w;
  }

  // prefetch current O tile (RMW) while staging completes
  f32x4 racc[8];
#pragma unroll
  for (int ci = 0; ci < 8; ++ci) {
    const int c = cg + ci * 4;
    f32x4 r;
#pragma unroll
    for (int hh = 0; hh < 4; ++hh)
      r[hh] = O[pvh + (size_t)c * THW + (size_t)tq * HWP + (h0 + hh) * 64 + wq];
    racc[ci] = r;
  }
  __syncthreads();

#pragma unroll 2
  for (int p = 0; p < 64; ++p) {
    const int row = 71 + p - (wq <= p ? 1 : 0);  // 70..133, in-bounds always
    const float* pa = Ab + (size_t)row * THW + h0 * 64 + wq;
    f32x4 a;
    a.x = pa[0];
    a.y = pa[64];
    a.z = pa[128];
    a.w = pa[192];
    if (p == wq) a = (f32x4){0.f, 0.f, 0.f, 0.f};
#pragma unroll
    for (int ci = 0; ci < 8; ++ci) {
      const f32x4 v = *(const f32x4*)&slab[(cg + ci * 4) * 256 + p * 4];
      racc[ci] += a * v;
    }
  }

  // ---- store (RMW result) ----
#pragma unroll
  for (int ci = 0; ci < 8; ++ci) {
    const int c = cg + ci * 4;
#pragma unroll
    for (int hh = 0; hh < 4; ++hh)
      O[pvh + (size_t)c * THW + (size_t)tq * HWP + (h0 + hh) * 64 + wq] = racc[ci][hh];
  }
}

extern "C" void kernel_launch(void* const* d_in, const int* in_sizes, int n_in,
                              void* d_out, int out_size, void* d_ws, size_t ws_size,
                              hipStream_t stream) {
  const float* A = (const float*)d_in[0];     // [8*134][8][64][64]
  const float* V = (const float*)d_in[1];     // [256][8][64][64]
  const float* W = (const float*)d_in[2];     // [256][256] (o, c)
  const float* bias = (const float*)d_in[3];  // [256]
  float* out = (float*)d_out;                 // [256][8][64][64]
  float* pv = (float*)d_ws;                   // 32 MB scratch: pv[o][t][h][w]

  conv1x1_v2<<<dim3(1024), 256, 0, stream>>>(V, W, bias, pv);
  attn_th<<<dim3(256), 512, 0, stream>>>(A, pv, out);
  attn_w<<<dim3(1024), 256, 0, stream>>>(A, pv, out);
}